// Round 1
// baseline (3511.023 us; speedup 1.0000x reference)
//
#include <hip/hip_runtime.h>

// Buffers in ws (all float):
//   A : N*32   B : N*32   C : N*32   cnt : N
//
// Schedule:
//  L1: t1t(x)->A=ht1,C=res1 ; agg(A,ei_t)->C ; t1i(x)->A=hi1,B=0,cnt=0 ;
//      agg(A,ei_i)->B,cnt ; combine(C,B,cnt)->A (=h1)
//  L2: t2t(A)->B=ht2,C=res2 ; agg(B,ei_t)->C ; t2i(A)->B=hi2 ; memset A=0 ;
//      agg(B,ei_i)->A ; combine(C,A,cnt)->B (=h2) ; cls(B)->out

#define BLK 256

__global__ __launch_bounds__(BLK) void k_l1_t(
    const float* __restrict__ x,
    const float* __restrict__ Wt, const float* __restrict__ bt,
    const float* __restrict__ Wr, const float* __restrict__ br,
    float* __restrict__ A, float* __restrict__ C, int N) {
  __shared__ float sWt[192], sWr[192], sbt[32], sbr[32];
  int t = threadIdx.x;
  if (t < 192) { sWt[t] = Wt[t]; sWr[t] = Wr[t]; }
  else if (t < 224) { int j = t - 192; sbt[j] = bt[j]; sbr[j] = br[j]; }
  __syncthreads();
  int gid = blockIdx.x * BLK + t;
  if (gid >= N * 32) return;
  int n = gid >> 5, j = gid & 31;
  const float* xr = x + n * 6;
  float x0 = xr[0], x1 = xr[1], x2 = xr[2], x3 = xr[3], x4 = xr[4], x5 = xr[5];
  float at = sbt[j], ar = sbr[j];
  at += x0 * sWt[0 * 32 + j] + x1 * sWt[1 * 32 + j] + x2 * sWt[2 * 32 + j] +
        x3 * sWt[3 * 32 + j] + x4 * sWt[4 * 32 + j] + x5 * sWt[5 * 32 + j];
  ar += x0 * sWr[0 * 32 + j] + x1 * sWr[1 * 32 + j] + x2 * sWr[2 * 32 + j] +
        x3 * sWr[3 * 32 + j] + x4 * sWr[4 * 32 + j] + x5 * sWr[5 * 32 + j];
  A[gid] = at;
  C[gid] = ar;
}

__global__ __launch_bounds__(BLK) void k_l1_i(
    const float* __restrict__ x,
    const float* __restrict__ Wi, const float* __restrict__ bi,
    float* __restrict__ A, float* __restrict__ B, float* __restrict__ cnt,
    int N) {
  __shared__ float sW[192], sb[32];
  int t = threadIdx.x;
  if (t < 192) sW[t] = Wi[t];
  else if (t < 224) sb[t - 192] = bi[t - 192];
  __syncthreads();
  int gid = blockIdx.x * BLK + t;
  if (gid >= N * 32) return;
  int n = gid >> 5, j = gid & 31;
  const float* xr = x + n * 6;
  float a = sb[j];
  a += xr[0] * sW[0 * 32 + j] + xr[1] * sW[1 * 32 + j] + xr[2] * sW[2 * 32 + j] +
       xr[3] * sW[3 * 32 + j] + xr[4] * sW[4 * 32 + j] + xr[5] * sW[5 * 32 + j];
  A[gid] = a;
  B[gid] = 0.0f;
  if (j == 0) cnt[n] = 0.0f;
}

// 8 threads per edge; float4 gather, 4 scalar atomics.
__global__ __launch_bounds__(BLK) void k_agg(
    const float* __restrict__ feat, const int* __restrict__ ei, int E,
    float* __restrict__ acc, float* __restrict__ cnt) {
  int gid = blockIdx.x * BLK + threadIdx.x;
  int e = gid >> 3;
  if (e >= E) return;
  int sub = gid & 7;
  int s = ei[e];
  int d = ei[E + e];
  const float4 v = *(const float4*)(feat + s * 32 + sub * 4);
  float* a = acc + d * 32 + sub * 4;
  atomicAdd(a + 0, v.x);
  atomicAdd(a + 1, v.y);
  atomicAdd(a + 2, v.z);
  atomicAdd(a + 3, v.w);
  if (cnt != nullptr && sub == 0) atomicAdd(cnt + d, 1.0f);
}

__global__ __launch_bounds__(BLK) void k_combine(
    const float* __restrict__ accT, const float* __restrict__ accI,
    const float* __restrict__ cnt, float* __restrict__ out, int N) {
  int gid = blockIdx.x * BLK + threadIdx.x;
  if (gid >= N * 32) return;
  int n = gid >> 5;
  float inv = 1.0f / fmaxf(cnt[n], 1.0f);
  float v = accT[gid] + accI[gid] * inv;
  out[gid] = fmaxf(v, 0.0f);
}

__global__ __launch_bounds__(BLK) void k_l2_t(
    const float* __restrict__ h,
    const float* __restrict__ Wt, const float* __restrict__ bt,
    const float* __restrict__ Wr, const float* __restrict__ br,
    float* __restrict__ outT, float* __restrict__ outR, int N) {
  __shared__ float sWt[1024], sWr[1024], sb[64], hs[BLK];
  int t = threadIdx.x;
  for (int i = t; i < 1024; i += BLK) { sWt[i] = Wt[i]; sWr[i] = Wr[i]; }
  if (t < 32) { sb[t] = bt[t]; sb[32 + t] = br[t]; }
  int gid = blockIdx.x * BLK + t;
  if (gid < N * 32) hs[t] = h[gid];
  __syncthreads();
  if (gid >= N * 32) return;
  int j = t & 31, ln = t >> 5;
  float at = sb[j], ar = sb[32 + j];
#pragma unroll
  for (int k = 0; k < 32; ++k) {
    float hv = hs[ln * 32 + k];
    at += hv * sWt[k * 32 + j];
    ar += hv * sWr[k * 32 + j];
  }
  outT[gid] = at;
  outR[gid] = ar;
}

__global__ __launch_bounds__(BLK) void k_l2_i(
    const float* __restrict__ h,
    const float* __restrict__ Wi, const float* __restrict__ bi,
    float* __restrict__ outI, int N) {
  __shared__ float sW[1024], sb[32], hs[BLK];
  int t = threadIdx.x;
  for (int i = t; i < 1024; i += BLK) sW[i] = Wi[i];
  if (t < 32) sb[t] = bi[t];
  int gid = blockIdx.x * BLK + t;
  if (gid < N * 32) hs[t] = h[gid];
  __syncthreads();
  if (gid >= N * 32) return;
  int j = t & 31, ln = t >> 5;
  float a = sb[j];
#pragma unroll
  for (int k = 0; k < 32; ++k) a += hs[ln * 32 + k] * sW[k * 32 + j];
  outI[gid] = a;
}

__global__ __launch_bounds__(BLK) void k_cls(
    const float* __restrict__ h,
    const float* __restrict__ Wc, const float* __restrict__ bc,
    float* __restrict__ out, int N) {
  __shared__ float sW[224], sb[7];
  int t = threadIdx.x;
  if (t < 224) sW[t] = Wc[t];
  if (t < 7) sb[t] = bc[t];
  __syncthreads();
  int gid = blockIdx.x * BLK + t;
  if (gid >= N * 7) return;
  int n = gid / 7, j = gid - n * 7;
  const float* hr = h + n * 32;
  float a = sb[j];
#pragma unroll
  for (int k = 0; k < 32; ++k) a += hr[k] * sW[k * 7 + j];
  out[gid] = a;
}

extern "C" void kernel_launch(void* const* d_in, const int* in_sizes, int n_in,
                              void* d_out, int out_size, void* d_ws,
                              size_t ws_size, hipStream_t stream) {
  const float* x   = (const float*)d_in[0];
  const int* ei_t  = (const int*)d_in[1];
  const int* ei_i  = (const int*)d_in[2];
  const float* W1t = (const float*)d_in[3];
  const float* b1t = (const float*)d_in[4];
  const float* W1i = (const float*)d_in[5];
  const float* b1i = (const float*)d_in[6];
  const float* W1r = (const float*)d_in[7];
  const float* b1r = (const float*)d_in[8];
  const float* W2t = (const float*)d_in[9];
  const float* b2t = (const float*)d_in[10];
  const float* W2i = (const float*)d_in[11];
  const float* b2i = (const float*)d_in[12];
  const float* W2r = (const float*)d_in[13];
  const float* b2r = (const float*)d_in[14];
  const float* Wc  = (const float*)d_in[15];
  const float* bc  = (const float*)d_in[16];
  float* out = (float*)d_out;

  const int N = in_sizes[0] / 6;
  const int E = in_sizes[1] / 2;   // edge_index is [2, E]
  const int Ei = in_sizes[2] / 2;

  float* A = (float*)d_ws;
  float* B = A + (size_t)N * 32;
  float* C = B + (size_t)N * 32;
  float* cnt = C + (size_t)N * 32;

  const int gN32 = (N * 32 + BLK - 1) / BLK;
  const int gEt  = (E * 8 + BLK - 1) / BLK;
  const int gEi  = (Ei * 8 + BLK - 1) / BLK;
  const int gN7  = (N * 7 + BLK - 1) / BLK;

  // ---- Layer 1 ----
  k_l1_t<<<gN32, BLK, 0, stream>>>(x, W1t, b1t, W1r, b1r, A, C, N);
  k_agg<<<gEt, BLK, 0, stream>>>(A, ei_t, E, C, nullptr);
  k_l1_i<<<gN32, BLK, 0, stream>>>(x, W1i, b1i, A, B, cnt, N);
  k_agg<<<gEi, BLK, 0, stream>>>(A, ei_i, Ei, B, cnt);
  k_combine<<<gN32, BLK, 0, stream>>>(C, B, cnt, A, N);  // A = h1

  // ---- Layer 2 ----
  k_l2_t<<<gN32, BLK, 0, stream>>>(A, W2t, b2t, W2r, b2r, B, C, N);
  k_agg<<<gEt, BLK, 0, stream>>>(B, ei_t, E, C, nullptr);
  k_l2_i<<<gN32, BLK, 0, stream>>>(A, W2i, b2i, B, N);  // B = hi2
  hipMemsetAsync(A, 0, (size_t)N * 32 * sizeof(float), stream);
  k_agg<<<gEi, BLK, 0, stream>>>(B, ei_i, Ei, A, nullptr);
  k_combine<<<gN32, BLK, 0, stream>>>(C, A, cnt, B, N);  // B = h2

  // ---- Classifier ----
  k_cls<<<gN7, BLK, 0, stream>>>(B, Wc, bc, out, N);
}

// Round 2
// 836.894 us; speedup vs baseline: 4.1953x; 4.1953x over previous
//
#include <hip/hip_runtime.h>

// Strategy: CSR-gather instead of scatter-atomics.
//  Per call: build CSR for each edge type (hist -> scan -> scatter),
//  then per layer: one transform kernel (3 linears), one fused gather kernel
//  (sum-agg + mean-agg + residual + relu, written in-place into res buffer).
//
// ws layout (4-byte elems):
//   A[N*32] ht | B[N*32] hi | C[N*32] res/h | histT[N] histI[N]
//   startT[N] startI[N] cursor[N] bsums[1024] | csrT[E] csrI[Ei]

#define BLK 256

__global__ __launch_bounds__(BLK) void k_hist(const int* __restrict__ ei,
                                              int E, int* __restrict__ hist) {
  int e = blockIdx.x * BLK + threadIdx.x;
  if (e >= E) return;
  atomicAdd(&hist[ei[E + e]], 1);
}

// block scans 1024 elements (256 threads x 4)
__global__ __launch_bounds__(BLK) void k_scan1(const int* __restrict__ in,
                                               int* __restrict__ out,
                                               int* __restrict__ bsums, int n) {
  __shared__ int s[BLK];
  int b = blockIdx.x, t = threadIdx.x;
  int base = b * 1024 + t * 4;
  int v0 = (base + 0 < n) ? in[base + 0] : 0;
  int v1 = (base + 1 < n) ? in[base + 1] : 0;
  int v2 = (base + 2 < n) ? in[base + 2] : 0;
  int v3 = (base + 3 < n) ? in[base + 3] : 0;
  int tsum = v0 + v1 + v2 + v3;
  s[t] = tsum;
  __syncthreads();
  for (int off = 1; off < BLK; off <<= 1) {
    int x = (t >= off) ? s[t - off] : 0;
    __syncthreads();
    s[t] += x;
    __syncthreads();
  }
  int excl = s[t] - tsum;
  if (t == BLK - 1) bsums[b] = s[BLK - 1];
  if (base + 0 < n) out[base + 0] = excl;
  if (base + 1 < n) out[base + 1] = excl + v0;
  if (base + 2 < n) out[base + 2] = excl + v0 + v1;
  if (base + 3 < n) out[base + 3] = excl + v0 + v1 + v2;
}

// single block, exclusive-scans up to 1024 block sums in place
__global__ __launch_bounds__(1024) void k_scan2(int* __restrict__ bsums,
                                                int nb) {
  __shared__ int s[1024];
  int t = threadIdx.x;
  int v = (t < nb) ? bsums[t] : 0;
  s[t] = v;
  __syncthreads();
  for (int off = 1; off < 1024; off <<= 1) {
    int x = (t >= off) ? s[t - off] : 0;
    __syncthreads();
    s[t] += x;
    __syncthreads();
  }
  if (t < nb) bsums[t] = s[t] - v;
}

__global__ __launch_bounds__(BLK) void k_scan3(int* __restrict__ out,
                                               const int* __restrict__ bsums,
                                               int* __restrict__ cursor,
                                               int n) {
  int i = blockIdx.x * BLK + threadIdx.x;
  if (i >= n) return;
  int v = out[i] + bsums[i >> 10];
  out[i] = v;
  cursor[i] = v;
}

__global__ __launch_bounds__(BLK) void k_scatter(const int* __restrict__ ei,
                                                 int E, int* __restrict__ cursor,
                                                 int* __restrict__ csr) {
  int e = blockIdx.x * BLK + threadIdx.x;
  if (e >= E) return;
  int d = ei[E + e];
  int pos = atomicAdd(&cursor[d], 1);
  csr[pos] = ei[e];
}

// layer-1 transforms: x[N,6] -> A=ht, B=hi, C=res
__global__ __launch_bounds__(BLK) void k_l1(
    const float* __restrict__ x, const float* __restrict__ Wt,
    const float* __restrict__ bt, const float* __restrict__ Wi,
    const float* __restrict__ bi, const float* __restrict__ Wr,
    const float* __restrict__ br, float* __restrict__ A, float* __restrict__ B,
    float* __restrict__ C, int N) {
  __shared__ float sWt[192], sWi[192], sWr[192], sb[96], sx[48];
  int t = threadIdx.x;
  if (t < 192) { sWt[t] = Wt[t]; sWi[t] = Wi[t]; sWr[t] = Wr[t]; }
  if (t < 32) { sb[t] = bt[t]; sb[32 + t] = bi[t]; sb[64 + t] = br[t]; }
  int gid = blockIdx.x * BLK + t;
  int nodeBase = (blockIdx.x * BLK) >> 5;
  if (t < 48) {
    int idx = nodeBase * 6 + t;
    if (idx < N * 6) sx[t] = x[idx];
  }
  __syncthreads();
  if (gid >= N * 32) return;
  int j = gid & 31, ln = t >> 5;
  const float* xr = sx + ln * 6;
  float at = sb[j], ai = sb[32 + j], ar = sb[64 + j];
#pragma unroll
  for (int k = 0; k < 6; ++k) {
    float xv = xr[k];
    at += xv * sWt[k * 32 + j];
    ai += xv * sWi[k * 32 + j];
    ar += xv * sWr[k * 32 + j];
  }
  A[gid] = at;
  B[gid] = ai;
  C[gid] = ar;
}

// layer-2 transforms: h=C[N,32] -> A=ht, B=hi, C=res (in-place safe via LDS)
__global__ __launch_bounds__(BLK) void k_l2(
    const float* __restrict__ h, const float* __restrict__ Wt,
    const float* __restrict__ bt, const float* __restrict__ Wi,
    const float* __restrict__ bi, const float* __restrict__ Wr,
    const float* __restrict__ br, float* __restrict__ A, float* __restrict__ B,
    float* __restrict__ C, int N) {
  __shared__ float sWt[1024], sWi[1024], sWr[1024], sb[96], hs[BLK];
  int t = threadIdx.x;
  for (int i = t; i < 1024; i += BLK) {
    sWt[i] = Wt[i];
    sWi[i] = Wi[i];
    sWr[i] = Wr[i];
  }
  if (t < 32) { sb[t] = bt[t]; sb[32 + t] = bi[t]; sb[64 + t] = br[t]; }
  int gid = blockIdx.x * BLK + t;
  hs[t] = (gid < N * 32) ? h[gid] : 0.0f;
  __syncthreads();
  if (gid >= N * 32) return;
  int j = t & 31, ln = t >> 5;
  float at = sb[j], ai = sb[32 + j], ar = sb[64 + j];
#pragma unroll
  for (int k = 0; k < 32; ++k) {
    float hv = hs[ln * 32 + k];
    at += hv * sWt[k * 32 + j];
    ai += hv * sWi[k * 32 + j];
    ar += hv * sWr[k * 32 + j];
  }
  A[gid] = at;
  B[gid] = ai;
  C[gid] = ar;
}

// fused gather: out = relu(sum_T(ht) + mean_I(hi) + res), written into C
__global__ __launch_bounds__(BLK) void k_gather(
    const float* __restrict__ A, const float* __restrict__ B,
    float* __restrict__ C, const int* __restrict__ startT,
    const int* __restrict__ histT, const int* __restrict__ csrT,
    const int* __restrict__ startI, const int* __restrict__ histI,
    const int* __restrict__ csrI, int N) {
  int gid = blockIdx.x * BLK + threadIdx.x;
  int n = gid >> 3;
  if (n >= N) return;
  int sub = gid & 7;
  float4 accT = {0.f, 0.f, 0.f, 0.f};
  {
    int s0 = startT[n], dT = histT[n];
    const int* ct = csrT + s0;
    for (int k = 0; k < dT; ++k) {
      int src = ct[k];
      const float4 v = *(const float4*)(A + src * 32 + sub * 4);
      accT.x += v.x; accT.y += v.y; accT.z += v.z; accT.w += v.w;
    }
  }
  float4 accI = {0.f, 0.f, 0.f, 0.f};
  int dI;
  {
    int s1 = startI[n];
    dI = histI[n];
    const int* ci = csrI + s1;
    for (int k = 0; k < dI; ++k) {
      int src = ci[k];
      const float4 v = *(const float4*)(B + src * 32 + sub * 4);
      accI.x += v.x; accI.y += v.y; accI.z += v.z; accI.w += v.w;
    }
  }
  float inv = 1.0f / fmaxf((float)dI, 1.0f);
  float* cp = C + n * 32 + sub * 4;
  const float4 r = *(const float4*)cp;
  float4 o;
  o.x = fmaxf(accT.x + accI.x * inv + r.x, 0.f);
  o.y = fmaxf(accT.y + accI.y * inv + r.y, 0.f);
  o.z = fmaxf(accT.z + accI.z * inv + r.z, 0.f);
  o.w = fmaxf(accT.w + accI.w * inv + r.w, 0.f);
  *(float4*)cp = o;
}

__global__ __launch_bounds__(BLK) void k_cls(const float* __restrict__ h,
                                             const float* __restrict__ Wc,
                                             const float* __restrict__ bc,
                                             float* __restrict__ out, int N) {
  __shared__ float sW[224], sb[7];
  int t = threadIdx.x;
  if (t < 224) sW[t] = Wc[t];
  if (t < 7) sb[t] = bc[t];
  __syncthreads();
  int gid = blockIdx.x * BLK + t;
  if (gid >= N * 7) return;
  int n = gid / 7, j = gid - n * 7;
  const float* hr = h + n * 32;
  float a = sb[j];
#pragma unroll
  for (int k = 0; k < 32; ++k) a += hr[k] * sW[k * 7 + j];
  out[gid] = a;
}

extern "C" void kernel_launch(void* const* d_in, const int* in_sizes, int n_in,
                              void* d_out, int out_size, void* d_ws,
                              size_t ws_size, hipStream_t stream) {
  const float* x   = (const float*)d_in[0];
  const int* ei_t  = (const int*)d_in[1];
  const int* ei_i  = (const int*)d_in[2];
  const float* W1t = (const float*)d_in[3];
  const float* b1t = (const float*)d_in[4];
  const float* W1i = (const float*)d_in[5];
  const float* b1i = (const float*)d_in[6];
  const float* W1r = (const float*)d_in[7];
  const float* b1r = (const float*)d_in[8];
  const float* W2t = (const float*)d_in[9];
  const float* b2t = (const float*)d_in[10];
  const float* W2i = (const float*)d_in[11];
  const float* b2i = (const float*)d_in[12];
  const float* W2r = (const float*)d_in[13];
  const float* b2r = (const float*)d_in[14];
  const float* Wc  = (const float*)d_in[15];
  const float* bc  = (const float*)d_in[16];
  float* out = (float*)d_out;

  const int N  = in_sizes[0] / 6;
  const int E  = in_sizes[1] / 2;
  const int Ei = in_sizes[2] / 2;

  float* A = (float*)d_ws;
  float* B = A + (size_t)N * 32;
  float* C = B + (size_t)N * 32;
  int* histT  = (int*)(C + (size_t)N * 32);
  int* histI  = histT + N;
  int* startT = histI + N;
  int* startI = startT + N;
  int* cursor = startI + N;
  int* bsums  = cursor + N;
  int* csrT   = bsums + 1024;
  int* csrI   = csrT + E;

  const int gN32 = (N * 32 + BLK - 1) / BLK;
  const int gEt  = (E + BLK - 1) / BLK;
  const int gEi  = (Ei + BLK - 1) / BLK;
  const int gN   = (N + BLK - 1) / BLK;
  const int gN8  = (N * 8 + BLK - 1) / BLK;
  const int gN7  = (N * 7 + BLK - 1) / BLK;
  const int nbT  = (N + 1023) / 1024;

  // ---- CSR build ----
  hipMemsetAsync(histT, 0, (size_t)2 * N * sizeof(int), stream);
  k_hist<<<gEt, BLK, 0, stream>>>(ei_t, E, histT);
  k_hist<<<gEi, BLK, 0, stream>>>(ei_i, Ei, histI);

  k_scan1<<<nbT, BLK, 0, stream>>>(histT, startT, bsums, N);
  k_scan2<<<1, 1024, 0, stream>>>(bsums, nbT);
  k_scan3<<<gN, BLK, 0, stream>>>(startT, bsums, cursor, N);
  k_scatter<<<gEt, BLK, 0, stream>>>(ei_t, E, cursor, csrT);

  k_scan1<<<nbT, BLK, 0, stream>>>(histI, startI, bsums, N);
  k_scan2<<<1, 1024, 0, stream>>>(bsums, nbT);
  k_scan3<<<gN, BLK, 0, stream>>>(startI, bsums, cursor, N);
  k_scatter<<<gEi, BLK, 0, stream>>>(ei_i, Ei, cursor, csrI);

  // ---- Layer 1 ----
  k_l1<<<gN32, BLK, 0, stream>>>(x, W1t, b1t, W1i, b1i, W1r, b1r, A, B, C, N);
  k_gather<<<gN8, BLK, 0, stream>>>(A, B, C, startT, histT, csrT, startI,
                                    histI, csrI, N);  // C = h1

  // ---- Layer 2 ----
  k_l2<<<gN32, BLK, 0, stream>>>(C, W2t, b2t, W2i, b2i, W2r, b2r, A, B, C, N);
  k_gather<<<gN8, BLK, 0, stream>>>(A, B, C, startT, histT, csrT, startI,
                                    histI, csrI, N);  // C = h2

  // ---- Classifier ----
  k_cls<<<gN7, BLK, 0, stream>>>(C, Wc, bc, out, N);
}